// Round 5
// baseline (596.499 us; speedup 1.0000x reference)
//
#include <hip/hip_runtime.h>
#include <math.h>

#define Bsz 128
#define Nn  512
#define Fd  64
#define Dd  64
#define Kk  20
#define BN  (Bsz*Nn)   // 65536
#define NCPY 32        // replicated stat accumulators
#define NBLK 1024u     // k234 grid: 4 blocks/CU x 256 CUs -> all co-resident (spin-barrier safe)
#define ET_STRIDE 129  // 64x129 f32 transposed tile: writes & reads 2 lanes/bank = conflict-free
#define SMEM_BYTES (64*ET_STRIDE*4 + 256*4)   // 33024 + 1024 = 34048 -> 4 blocks/CU

__device__ __forceinline__ float leaky(float v){ return (v >= 0.f) ? v : 0.2f*v; }

// wave argmax (max value, lowest index on ties) via DPP: row_shr 1/2/4/8 + row_bcast15/31.
__device__ __forceinline__ int wave_argmax_idx(float v, int idx){
  int vi = __float_as_int(v);
#define DPP_STEP(CTRL) { \
    int nv = __builtin_amdgcn_update_dpp(vi,  vi,  CTRL, 0xF, 0xF, false); \
    int ni = __builtin_amdgcn_update_dpp(idx, idx, CTRL, 0xF, 0xF, false); \
    float fnv = __int_as_float(nv), fov = __int_as_float(vi); \
    bool take = (fnv > fov) || ((fnv == fov) && (ni < idx)); \
    vi = take ? nv : vi; idx = take ? ni : idx; \
  }
  DPP_STEP(0x111)  // row_shr:1
  DPP_STEP(0x112)  // row_shr:2
  DPP_STEP(0x114)  // row_shr:4
  DPP_STEP(0x118)  // row_shr:8
  DPP_STEP(0x142)  // row_bcast15
  DPP_STEP(0x143)  // row_bcast31 -> lane 63 has full-wave result
#undef DPP_STEP
  return __builtin_amdgcn_readlane(idx, 63);
}

// ==== K1: blocks [0,128) = topk (runs first, overlaps linear); [128,1152) = g=x@W + scores ====
__global__ __launch_bounds__(256) void k1(const float* __restrict__ x,
    const float* __restrict__ W, const float* __restrict__ embed,
    const float* __restrict__ att_i, const float* __restrict__ att_j,
    const float* __restrict__ aem_i, const float* __restrict__ aem_j,
    float* __restrict__ g, float* __restrict__ s_i, float* __restrict__ s_j,
    int* __restrict__ topk, float* __restrict__ stats){
  __shared__ __align__(16) char smem[SMEM_BYTES];   // union: linear uses 17.4KB, topk 34KB
  int tid = threadIdx.x, b = blockIdx.x;

  if (b >= 128){
    // ---------- linear transform + attention scores ----------
    int bl = b - 128;
    float4* sW   = (float4*)smem;              // 16KB
    float4* sai  = (float4*)(smem + 16384);
    float4* saj  = sai + 16;
    float4* semi = saj + 16;
    float4* semj = semi + 16;
    const float4* W4 = (const float4*)W;
    #pragma unroll
    for (int t = 0; t < 4; t++) sW[tid + 256*t] = W4[tid + 256*t];
    if (tid < 16){
      sai[tid]  = ((const float4*)att_i)[tid];
      saj[tid]  = ((const float4*)att_j)[tid];
      semi[tid] = ((const float4*)aem_i)[tid];
      semj[tid] = ((const float4*)aem_j)[tid];
    }
    __syncthreads();
    int rowgrp = tid >> 4, cg_ = tid & 15;
    int row0 = bl*64 + rowgrp*4;
    float4 acc0={0,0,0,0}, acc1={0,0,0,0}, acc2={0,0,0,0}, acc3={0,0,0,0};
    const float4* xr0 = (const float4*)(x + (row0+0)*Fd);
    const float4* xr1 = (const float4*)(x + (row0+1)*Fd);
    const float4* xr2 = (const float4*)(x + (row0+2)*Fd);
    const float4* xr3 = (const float4*)(x + (row0+3)*Fd);
    for (int qk = 0; qk < 16; qk++){
      float4 x0 = xr0[qk], x1 = xr1[qk], x2 = xr2[qk], x3 = xr3[qk];
      float xs0[4] = {x0.x,x0.y,x0.z,x0.w};
      float xs1[4] = {x1.x,x1.y,x1.z,x1.w};
      float xs2[4] = {x2.x,x2.y,x2.z,x2.w};
      float xs3[4] = {x3.x,x3.y,x3.z,x3.w};
      #pragma unroll
      for (int s = 0; s < 4; s++){
        float4 w4 = sW[(4*qk + s)*16 + cg_];
        acc0.x += xs0[s]*w4.x; acc0.y += xs0[s]*w4.y; acc0.z += xs0[s]*w4.z; acc0.w += xs0[s]*w4.w;
        acc1.x += xs1[s]*w4.x; acc1.y += xs1[s]*w4.y; acc1.z += xs1[s]*w4.z; acc1.w += xs1[s]*w4.w;
        acc2.x += xs2[s]*w4.x; acc2.y += xs2[s]*w4.y; acc2.z += xs2[s]*w4.z; acc2.w += xs2[s]*w4.w;
        acc3.x += xs3[s]*w4.x; acc3.y += xs3[s]*w4.y; acc3.z += xs3[s]*w4.z; acc3.w += xs3[s]*w4.w;
      }
    }
    float4 ai = sai[cg_], aj = saj[cg_], emi = semi[cg_], emj = semj[cg_];
    float4 avv[4] = {acc0, acc1, acc2, acc3};
    #pragma unroll
    for (int r = 0; r < 4; r++){
      int row = row0 + r;
      int node = row & (Nn-1);
      float4 a4 = avv[r];
      float4 e4 = ((const float4*)embed)[node*16 + cg_];
      float si = a4.x*ai.x + a4.y*ai.y + a4.z*ai.z + a4.w*ai.w
               + e4.x*emi.x + e4.y*emi.y + e4.z*emi.z + e4.w*emi.w;
      float sj = a4.x*aj.x + a4.y*aj.y + a4.z*aj.z + a4.w*aj.w
               + e4.x*emj.x + e4.y*emj.y + e4.z*emj.z + e4.w*emj.w;
      #pragma unroll
      for (int o = 1; o < 16; o <<= 1){
        si += __shfl_xor(si, o, 64);
        sj += __shfl_xor(sj, o, 64);
      }
      if (cg_ == 0){ s_i[row] = si; s_j[row] = sj; }
      ((float4*)(g + row*Dd))[cg_] = a4;
    }
  } else {
    // ---------- topk: 4 waves, one row each; tiled LDS-transposed candidates ----------
    int bb = b;
    if (b == 0){                                // zero stats + barrier ctrl (drops memset dispatch)
      #pragma unroll 1
      for (int i = tid; i < NCPY*256 + 16; i += 256) stats[i] = 0.f;
    }
    float* eT = (float*)smem;                   // [64][ET_STRIDE] normalized, transposed
    float* se = (float*)(smem + 64*ET_STRIDE*4);// [256] raw query rows (norm is argmax-invariant)
    int wv = tid >> 6, lane = tid & 63;
    se[tid] = embed[bb*256 + tid];              // this block's 4 query rows, coalesced
    const float4* emb4 = (const float4*)embed;
    float av[8];                                // av[rep] = score of candidate rep*64+lane
    #pragma unroll
    for (int tt = 0; tt < 4; tt++){             // 4 tiles x 128 candidate rows
      float4 stg[8];
      #pragma unroll
      for (int j = 0; j < 8; j++)               // fully coalesced: 4KB contiguous per instr
        stg[j] = emb4[tt*2048 + j*256 + tid];   // = row (tt*128 + j*16 + tid>>4), d0=(tid&15)*4
      __syncthreads();                          // prev tile fully consumed before overwrite
      #pragma unroll
      for (int j = 0; j < 8; j++){
        float4 v = stg[j];
        float ss = v.x*v.x + v.y*v.y + v.z*v.z + v.w*v.w;
        #pragma unroll
        for (int o = 1; o < 16; o <<= 1) ss += __shfl_xor(ss, o, 64);  // row sumsq over 16 lanes
        float rn = 1.f/(sqrtf(ss) + 1e-12f);
        int row_local = j*16 + (tid >> 4);
        int d0 = (tid & 15)*4;
        eT[(d0+0)*ET_STRIDE + row_local] = v.x*rn;
        eT[(d0+1)*ET_STRIDE + row_local] = v.y*rn;
        eT[(d0+2)*ET_STRIDE + row_local] = v.z*rn;
        eT[(d0+3)*ET_STRIDE + row_local] = v.w*rn;
      }
      __syncthreads();
      const float4* sef4 = (const float4*)(se + wv*64);
      float a0 = 0.f, a1 = 0.f;
      #pragma unroll
      for (int d4 = 0; d4 < 16; d4++){
        float4 q4 = sef4[d4];                   // uniform addr -> broadcast, conflict-free
        int d = d4*4;
        a0 += q4.x*eT[(d+0)*ET_STRIDE + lane] + q4.y*eT[(d+1)*ET_STRIDE + lane]
            + q4.z*eT[(d+2)*ET_STRIDE + lane] + q4.w*eT[(d+3)*ET_STRIDE + lane];
        a1 += q4.x*eT[(d+0)*ET_STRIDE + 64 + lane] + q4.y*eT[(d+1)*ET_STRIDE + 64 + lane]
            + q4.z*eT[(d+2)*ET_STRIDE + 64 + lane] + q4.w*eT[(d+3)*ET_STRIDE + 64 + lane];
      }
      av[2*tt]   = a0;
      av[2*tt+1] = a1;
    }
    int row = bb*4 + wv;
    #pragma unroll 1
    for (int t = 0; t < Kk; t++){
      float bv = av[0]; int br = 0;
      #pragma unroll
      for (int rep = 1; rep < 8; rep++)
        if (av[rep] > bv){ bv = av[rep]; br = rep; }   // strict > = lowest c per lane
      int ci = br*64 + lane;
      int win = wave_argmax_idx(bv, ci);        // DPP reduce, lowest-index tie-break
      if (lane == 0) topk[row*Kk + t] = win;
      int wr = win >> 6;
      if ((win & 63) == lane){
        #pragma unroll
        for (int rep = 0; rep < 8; rep++)
          if (rep == wr) av[rep] = -INFINITY;
      }
    }
  }
}

// ====== K234 (fused, manual device barrier): softmax+gather -> BN1 -> embed-mul -> BN2 -> head ======
// NOT cooperative (graph-capture-safe plain launch). 1024 blocks, __launch_bounds__(256,4)
// -> 4 blocks/CU guaranteed resident (LDS 5.9KB, VGPR<=128) -> spin barrier cannot deadlock.
// Barrier: ACQ_REL arrival counter; last block computes BN params from replicated stats
// (agent-scope loads: coherent across per-XCD L2s), publishes to bnp, release-stores flag.
// agg buffer eliminated (was 16MB write + 32MB read + 2 dispatches + memset).
__global__ __launch_bounds__(256, 4) void k234(const float* __restrict__ g,
    const float* __restrict__ s_i, const float* __restrict__ s_j,
    const int* __restrict__ topk, const float* __restrict__ bias,
    const float* __restrict__ embed, const float* __restrict__ bn1g,
    const float* __restrict__ bn1b, const float* __restrict__ bn2g,
    const float* __restrict__ bn2b, const float* __restrict__ outW,
    const float* __restrict__ outb, float* __restrict__ stats,
    unsigned* __restrict__ ctrl, float* __restrict__ bnp,
    float* __restrict__ out){
  __shared__ float  swt[4][4][24];
  __shared__ int    sji[4][4][24];
  __shared__ float4 sred_s[4][16], sred_q[4][16];
  __shared__ float4 sbias[16];
  __shared__ float  ssc[64], ssh[64];
  __shared__ int    slast;
  int tid = threadIdx.x, wv = tid >> 6, lane = tid & 63;
  if (tid < 16) sbias[tid] = ((const float4*)bias)[tid];
  __syncthreads();
  // bid%8 preserved -> each batch's g-slab stays on one XCD's L2
  int bid = blockIdx.x;
  int xcd = bid & 7, q = bid >> 3;             // q 0..127
  int batch = xcd*16 + (q & 15);
  int eighth = q >> 4;                         // 0..7
  int base = batch*Nn;
  int node0 = eighth*64 + wv*16;               // 16 nodes per wave = 4 rounds x 4
  const float4* g4 = (const float4*)g;
  int h = lane >> 4, c = lane & 15;
  int half = lane >> 5, ln = lane & 31;        // pair-softmax: 2 nodes per round per half
  float4 accs[4];                              // fully-unrolled static indexing -> stays in regs
  float4 s4 = {0,0,0,0}, q4 = {0,0,0,0};
  // ---------------- phase A: attention softmax + gather-aggregate ----------------
  #pragma unroll
  for (int gI = 0; gI < 4; gI++){
    #pragma unroll
    for (int pr = 0; pr < 2; pr++){            // 2 pairs = 4 nodes per round
      int node = node0 + gI*4 + pr*2 + half;
      int dest = base + node;
      float si_d = s_i[dest];
      float lg = -INFINITY; int j = node;
      if (ln < Kk){
        j = topk[node*Kk + ln];
        if (j != node) lg = leaky(si_d + s_j[base + j]);  // self in topk masked
      } else if (ln == Kk){
        lg = leaky(si_d + s_j[dest]);                     // appended self loop
      }
      float m = lg;
      #pragma unroll
      for (int o = 16; o; o >>= 1) m = fmaxf(m, __shfl_xor(m, o, 64));  // per-half reduce
      float e_ = (ln <= Kk) ? __expf(lg - m) : 0.f;
      float denom = e_;
      #pragma unroll
      for (int o = 16; o; o >>= 1) denom += __shfl_xor(denom, o, 64);
      if (ln < 24){
        swt[wv][pr*2+half][ln] = (ln <= Kk) ? e_/denom : 0.f;
        sji[wv][pr*2+half][ln] = j;
      }
    }
    float la[24]; int ja[24];                 // wave-synchronous LDS readback
    const float4* lv = (const float4*)swt[wv][h];
    const int4*   jv = (const int4*)sji[wv][h];
    #pragma unroll
    for (int qq = 0; qq < 6; qq++){
      float4 f = lv[qq]; la[4*qq]=f.x; la[4*qq+1]=f.y; la[4*qq+2]=f.z; la[4*qq+3]=f.w;
      int4  ii = jv[qq]; ja[4*qq]=ii.x; ja[4*qq+1]=ii.y; ja[4*qq+2]=ii.z; ja[4*qq+3]=ii.w;
    }
    float4 acc = sbias[c];
    #pragma unroll
    for (int e = 0; e <= Kk; e++){
      float4 gv = g4[(base + ja[e])*16 + c];  // L2-resident batch slab
      acc.x += la[e]*gv.x; acc.y += la[e]*gv.y; acc.z += la[e]*gv.z; acc.w += la[e]*gv.w;
    }
    accs[gI] = acc;
    s4.x += acc.x; s4.y += acc.y; s4.z += acc.z; s4.w += acc.w;
    q4.x += acc.x*acc.x; q4.y += acc.y*acc.y; q4.z += acc.z*acc.z; q4.w += acc.w*acc.w;
  }
  #pragma unroll
  for (int o = 16; o <= 32; o <<= 1){
    s4.x += __shfl_xor(s4.x,o,64); s4.y += __shfl_xor(s4.y,o,64);
    s4.z += __shfl_xor(s4.z,o,64); s4.w += __shfl_xor(s4.w,o,64);
    q4.x += __shfl_xor(q4.x,o,64); q4.y += __shfl_xor(q4.y,o,64);
    q4.z += __shfl_xor(q4.z,o,64); q4.w += __shfl_xor(q4.w,o,64);
  }
  if (lane < 16){ sred_s[wv][lane] = s4; sred_q[wv][lane] = q4; }
  __syncthreads();
  float* sc = stats + (bid & (NCPY-1))*256;   // replicated accumulators
  if (wv == 0 && lane < 16){
    float4 a = sred_s[0][lane];
    #pragma unroll
    for (int w = 1; w < 4; w++){ float4 t = sred_s[w][lane]; a.x+=t.x; a.y+=t.y; a.z+=t.z; a.w+=t.w; }
    atomicAdd(&sc[lane*4+0], a.x); atomicAdd(&sc[lane*4+1], a.y);
    atomicAdd(&sc[lane*4+2], a.z); atomicAdd(&sc[lane*4+3], a.w);
  }
  if (wv == 1 && lane < 16){
    float4 a = sred_q[0][lane];
    #pragma unroll
    for (int w = 1; w < 4; w++){ float4 t = sred_q[w][lane]; a.x+=t.x; a.y+=t.y; a.z+=t.z; a.w+=t.w; }
    atomicAdd(&sc[64+lane*4+0], a.x); atomicAdd(&sc[64+lane*4+1], a.y);
    atomicAdd(&sc[64+lane*4+2], a.z); atomicAdd(&sc[64+lane*4+3], a.w);
  }
  // ---------------- barrier 1: stats complete -> BN1 params in bnp[0..127] ----------------
  __syncthreads();
  if (tid == 0){
    unsigned prev = __hip_atomic_fetch_add(&ctrl[0], 1u, __ATOMIC_ACQ_REL, __HIP_MEMORY_SCOPE_AGENT);
    slast = (prev == NBLK - 1u);
  }
  __syncthreads();
  if (slast){
    if (tid < 64){
      float s = 0.f, qq = 0.f;
      #pragma unroll
      for (int x = 0; x < NCPY; x++){
        s  += __hip_atomic_load(&stats[x*256 + tid],      __ATOMIC_RELAXED, __HIP_MEMORY_SCOPE_AGENT);
        qq += __hip_atomic_load(&stats[x*256 + 64 + tid], __ATOMIC_RELAXED, __HIP_MEMORY_SCOPE_AGENT);
      }
      float mu = s*(1.f/BN), var = qq*(1.f/BN) - mu*mu;
      float scv = bn1g[tid]/sqrtf(var + 1e-5f);
      __hip_atomic_store(&bnp[tid],      scv,                __ATOMIC_RELAXED, __HIP_MEMORY_SCOPE_AGENT);
      __hip_atomic_store(&bnp[64 + tid], bn1b[tid] - mu*scv, __ATOMIC_RELAXED, __HIP_MEMORY_SCOPE_AGENT);
    }
    __syncthreads();
    if (tid == 0) __hip_atomic_store(&ctrl[1], 1u, __ATOMIC_RELEASE, __HIP_MEMORY_SCOPE_AGENT);
  }
  if (tid == 0){
    while (__hip_atomic_load(&ctrl[1], __ATOMIC_ACQUIRE, __HIP_MEMORY_SCOPE_AGENT) == 0u)
      __builtin_amdgcn_s_sleep(8);
  }
  __syncthreads();
  if (tid < 64){
    ssc[tid] = __hip_atomic_load(&bnp[tid],      __ATOMIC_RELAXED, __HIP_MEMORY_SCOPE_AGENT);
    ssh[tid] = __hip_atomic_load(&bnp[64 + tid], __ATOMIC_RELAXED, __HIP_MEMORY_SCOPE_AGENT);
  }
  __syncthreads();
  // ---------------- phase B: BN1 apply + embed mul + BN2 stats ----------------
  float4 sc1 = ((const float4*)ssc)[c], sh1 = ((const float4*)ssh)[c];
  float4 s4b = {0,0,0,0}, q4b = {0,0,0,0};
  #pragma unroll
  for (int gI = 0; gI < 4; gI++){
    int node = node0 + gI*4 + h;
    float4 e4 = ((const float4*)embed)[node*16 + c];
    float4 v = accs[gI];
    v.x = fmaxf(v.x*sc1.x+sh1.x, 0.f)*e4.x;
    v.y = fmaxf(v.y*sc1.y+sh1.y, 0.f)*e4.y;
    v.z = fmaxf(v.z*sc1.z+sh1.z, 0.f)*e4.z;
    v.w = fmaxf(v.w*sc1.w+sh1.w, 0.f)*e4.w;
    accs[gI] = v;                              // h kept in registers for phase C
    s4b.x += v.x; s4b.y += v.y; s4b.z += v.z; s4b.w += v.w;
    q4b.x += v.x*v.x; q4b.y += v.y*v.y; q4b.z += v.z*v.z; q4b.w += v.w*v.w;
  }
  #pragma unroll
  for (int o = 16; o <= 32; o <<= 1){
    s4b.x += __shfl_xor(s4b.x,o,64); s4b.y += __shfl_xor(s4b.y,o,64);
    s4b.z += __shfl_xor(s4b.z,o,64); s4b.w += __shfl_xor(s4b.w,o,64);
    q4b.x += __shfl_xor(q4b.x,o,64); q4b.y += __shfl_xor(q4b.y,o,64);
    q4b.z += __shfl_xor(q4b.z,o,64); q4b.w += __shfl_xor(q4b.w,o,64);
  }
  if (lane < 16){ sred_s[wv][lane] = s4b; sred_q[wv][lane] = q4b; }
  __syncthreads();
  if (wv == 0 && lane < 16){
    float4 a = sred_s[0][lane];
    #pragma unroll
    for (int w = 1; w < 4; w++){ float4 t = sred_s[w][lane]; a.x+=t.x; a.y+=t.y; a.z+=t.z; a.w+=t.w; }
    atomicAdd(&sc[128+lane*4+0], a.x); atomicAdd(&sc[128+lane*4+1], a.y);
    atomicAdd(&sc[128+lane*4+2], a.z); atomicAdd(&sc[128+lane*4+3], a.w);
  }
  if (wv == 1 && lane < 16){
    float4 a = sred_q[0][lane];
    #pragma unroll
    for (int w = 1; w < 4; w++){ float4 t = sred_q[w][lane]; a.x+=t.x; a.y+=t.y; a.z+=t.z; a.w+=t.w; }
    atomicAdd(&sc[192+lane*4+0], a.x); atomicAdd(&sc[192+lane*4+1], a.y);
    atomicAdd(&sc[192+lane*4+2], a.z); atomicAdd(&sc[192+lane*4+3], a.w);
  }
  // ---------------- barrier 2: BN2 stats complete -> params in bnp[128..255] ----------------
  __syncthreads();
  if (tid == 0){
    unsigned prev = __hip_atomic_fetch_add(&ctrl[2], 1u, __ATOMIC_ACQ_REL, __HIP_MEMORY_SCOPE_AGENT);
    slast = (prev == NBLK - 1u);
  }
  __syncthreads();
  if (slast){
    if (tid < 64){
      float s = 0.f, qq = 0.f;
      #pragma unroll
      for (int x = 0; x < NCPY; x++){
        s  += __hip_atomic_load(&stats[x*256 + 128 + tid], __ATOMIC_RELAXED, __HIP_MEMORY_SCOPE_AGENT);
        qq += __hip_atomic_load(&stats[x*256 + 192 + tid], __ATOMIC_RELAXED, __HIP_MEMORY_SCOPE_AGENT);
      }
      float mu = s*(1.f/BN), var = qq*(1.f/BN) - mu*mu;
      float scv = bn2g[tid]/sqrtf(var + 1e-5f);
      __hip_atomic_store(&bnp[128 + tid], scv,                __ATOMIC_RELAXED, __HIP_MEMORY_SCOPE_AGENT);
      __hip_atomic_store(&bnp[192 + tid], bn2b[tid] - mu*scv, __ATOMIC_RELAXED, __HIP_MEMORY_SCOPE_AGENT);
    }
    __syncthreads();
    if (tid == 0) __hip_atomic_store(&ctrl[3], 1u, __ATOMIC_RELEASE, __HIP_MEMORY_SCOPE_AGENT);
  }
  if (tid == 0){
    while (__hip_atomic_load(&ctrl[3], __ATOMIC_ACQUIRE, __HIP_MEMORY_SCOPE_AGENT) == 0u)
      __builtin_amdgcn_s_sleep(8);
  }
  __syncthreads();
  if (tid < 64){
    ssc[tid] = __hip_atomic_load(&bnp[128 + tid], __ATOMIC_RELAXED, __HIP_MEMORY_SCOPE_AGENT);
    ssh[tid] = __hip_atomic_load(&bnp[192 + tid], __ATOMIC_RELAXED, __HIP_MEMORY_SCOPE_AGENT);
  }
  __syncthreads();
  // ---------------- phase C: BN2 apply + output head ----------------
  float4 sc2 = ((const float4*)ssc)[c], sh2 = ((const float4*)ssh)[c];
  float4 ow  = ((const float4*)outW)[c];
  float ob = outb[0];
  #pragma unroll
  for (int gI = 0; gI < 4; gI++){
    float4 v = accs[gI];
    float t = fmaxf(v.x*sc2.x+sh2.x, 0.f)*ow.x
            + fmaxf(v.y*sc2.y+sh2.y, 0.f)*ow.y
            + fmaxf(v.z*sc2.z+sh2.z, 0.f)*ow.z
            + fmaxf(v.w*sc2.w+sh2.w, 0.f)*ow.w;
    #pragma unroll
    for (int o = 1; o < 16; o <<= 1) t += __shfl_xor(t, o, 64);   // reduce 16 c-chunks
    if (c == 0) out[base + node0 + gI*4 + h] = t + ob;
  }
}

extern "C" void kernel_launch(void* const* d_in, const int* in_sizes, int n_in,
                              void* d_out, int out_size, void* d_ws, size_t ws_size,
                              hipStream_t stream){
  const float* data  = (const float*)d_in[0];
  // d_in[1] = org_edge_index — unused by the reference computation
  const float* embed = (const float*)d_in[2];
  const float* W_lin = (const float*)d_in[3];
  const float* att_i = (const float*)d_in[4];
  const float* att_j = (const float*)d_in[5];
  const float* aem_i = (const float*)d_in[6];
  const float* aem_j = (const float*)d_in[7];
  const float* bias  = (const float*)d_in[8];
  const float* g1    = (const float*)d_in[9];
  const float* b1    = (const float*)d_in[10];
  const float* g2    = (const float*)d_in[11];
  const float* b2    = (const float*)d_in[12];
  const float* outW  = (const float*)d_in[13];
  const float* outb  = (const float*)d_in[14];
  float* out = (float*)d_out;

  float* ws    = (float*)d_ws;
  float* g     = ws;                       // 4,194,304 f32 (16 MB)
  float* s_i   = ws + 8388608;             // 65,536  (agg slot unused)
  float* s_j   = s_i + 65536;              // 65,536
  int*   tk    = (int*)(s_j + 65536);      // 10,240
  float* stats = (float*)(tk + Nn*Kk);     // NCPY x 256 f32 (zeroed by k1 block 0)
  unsigned* ctrl = (unsigned*)(stats + NCPY*256);  // 16 u32: barrier counters/flags (zeroed by k1)
  float* bnp   = (float*)(ctrl + 16);      // 256 f32: published BN1/BN2 scale+shift

  k1<<<1152, 256, 0, stream>>>(data, W_lin, embed, att_i, att_j, aem_i, aem_j,
                               g, s_i, s_j, tk, stats);
  k234<<<1024, 256, 0, stream>>>(g, s_i, s_j, tk, bias, embed, g1, b1, g2, b2,
                                 outW, outb, stats, ctrl, bnp, out);
}

// Round 6
// 151.182 us; speedup vs baseline: 3.9456x; 3.9456x over previous
//
#include <hip/hip_runtime.h>
#include <math.h>

#define Bsz 128
#define Nn  512
#define Fd  64
#define Dd  64
#define Kk  20
#define BN  (Bsz*Nn)   // 65536
#define NCPY 32        // replicated stat accumulators (2048 blocks / 32 = 64 adds/addr)
#define ET_STRIDE 129  // 64x129 f32 transposed tile: writes & reads 2 lanes/bank = conflict-free
#define SMEM_BYTES (64*ET_STRIDE*4 + 256*4)   // 33024 + 1024 = 34048 -> 4 blocks/CU

__device__ __forceinline__ float leaky(float v){ return (v >= 0.f) ? v : 0.2f*v; }

// wave argmax (max value, lowest index on ties) via DPP: row_shr 1/2/4/8 + row_bcast15/31.
// VALU-pipe instead of 6 dependent LDS-pipe shuffles. Lane 63 holds result.
__device__ __forceinline__ int wave_argmax_idx(float v, int idx){
  int vi = __float_as_int(v);
#define DPP_STEP(CTRL) { \
    int nv = __builtin_amdgcn_update_dpp(vi,  vi,  CTRL, 0xF, 0xF, false); \
    int ni = __builtin_amdgcn_update_dpp(idx, idx, CTRL, 0xF, 0xF, false); \
    float fnv = __int_as_float(nv), fov = __int_as_float(vi); \
    bool take = (fnv > fov) || ((fnv == fov) && (ni < idx)); \
    vi = take ? nv : vi; idx = take ? ni : idx; \
  }
  DPP_STEP(0x111)  // row_shr:1
  DPP_STEP(0x112)  // row_shr:2
  DPP_STEP(0x114)  // row_shr:4
  DPP_STEP(0x118)  // row_shr:8
  DPP_STEP(0x142)  // row_bcast15
  DPP_STEP(0x143)  // row_bcast31 -> lane 63 has full-wave result
#undef DPP_STEP
  return __builtin_amdgcn_readlane(idx, 63);
}

// ==== K1: blocks [0,128) = topk (runs first, overlaps linear); [128,1152) = g=x@W + scores ====
// Block 0 also zeroes the stats accumulators (drops the separate memset dispatch).
__global__ __launch_bounds__(256) void k1(const float* __restrict__ x,
    const float* __restrict__ W, const float* __restrict__ embed,
    const float* __restrict__ att_i, const float* __restrict__ att_j,
    const float* __restrict__ aem_i, const float* __restrict__ aem_j,
    float* __restrict__ g, float* __restrict__ s_i, float* __restrict__ s_j,
    int* __restrict__ topk, float* __restrict__ stats){
  __shared__ __align__(16) char smem[SMEM_BYTES];   // union: linear uses 17.4KB, topk 34KB
  int tid = threadIdx.x, b = blockIdx.x;

  if (b >= 128){
    // ---------- linear transform + attention scores ----------
    int bl = b - 128;
    float4* sW   = (float4*)smem;              // 16KB
    float4* sai  = (float4*)(smem + 16384);
    float4* saj  = sai + 16;
    float4* semi = saj + 16;
    float4* semj = semi + 16;
    const float4* W4 = (const float4*)W;
    #pragma unroll
    for (int t = 0; t < 4; t++) sW[tid + 256*t] = W4[tid + 256*t];
    if (tid < 16){
      sai[tid]  = ((const float4*)att_i)[tid];
      saj[tid]  = ((const float4*)att_j)[tid];
      semi[tid] = ((const float4*)aem_i)[tid];
      semj[tid] = ((const float4*)aem_j)[tid];
    }
    __syncthreads();
    int rowgrp = tid >> 4, cg_ = tid & 15;
    int row0 = bl*64 + rowgrp*4;
    float4 acc0={0,0,0,0}, acc1={0,0,0,0}, acc2={0,0,0,0}, acc3={0,0,0,0};
    const float4* xr0 = (const float4*)(x + (row0+0)*Fd);
    const float4* xr1 = (const float4*)(x + (row0+1)*Fd);
    const float4* xr2 = (const float4*)(x + (row0+2)*Fd);
    const float4* xr3 = (const float4*)(x + (row0+3)*Fd);
    for (int qk = 0; qk < 16; qk++){
      float4 x0 = xr0[qk], x1 = xr1[qk], x2 = xr2[qk], x3 = xr3[qk];
      float xs0[4] = {x0.x,x0.y,x0.z,x0.w};
      float xs1[4] = {x1.x,x1.y,x1.z,x1.w};
      float xs2[4] = {x2.x,x2.y,x2.z,x2.w};
      float xs3[4] = {x3.x,x3.y,x3.z,x3.w};
      #pragma unroll
      for (int s = 0; s < 4; s++){
        float4 w4 = sW[(4*qk + s)*16 + cg_];
        acc0.x += xs0[s]*w4.x; acc0.y += xs0[s]*w4.y; acc0.z += xs0[s]*w4.z; acc0.w += xs0[s]*w4.w;
        acc1.x += xs1[s]*w4.x; acc1.y += xs1[s]*w4.y; acc1.z += xs1[s]*w4.z; acc1.w += xs1[s]*w4.w;
        acc2.x += xs2[s]*w4.x; acc2.y += xs2[s]*w4.y; acc2.z += xs2[s]*w4.z; acc2.w += xs2[s]*w4.w;
        acc3.x += xs3[s]*w4.x; acc3.y += xs3[s]*w4.y; acc3.z += xs3[s]*w4.z; acc3.w += xs3[s]*w4.w;
      }
    }
    float4 ai = sai[cg_], aj = saj[cg_], emi = semi[cg_], emj = semj[cg_];
    float4 avv[4] = {acc0, acc1, acc2, acc3};
    #pragma unroll
    for (int r = 0; r < 4; r++){
      int row = row0 + r;
      int node = row & (Nn-1);
      float4 a4 = avv[r];
      float4 e4 = ((const float4*)embed)[node*16 + cg_];
      float si = a4.x*ai.x + a4.y*ai.y + a4.z*ai.z + a4.w*ai.w
               + e4.x*emi.x + e4.y*emi.y + e4.z*emi.z + e4.w*emi.w;
      float sj = a4.x*aj.x + a4.y*aj.y + a4.z*aj.z + a4.w*aj.w
               + e4.x*emj.x + e4.y*emj.y + e4.z*emj.z + e4.w*emj.w;
      #pragma unroll
      for (int o = 1; o < 16; o <<= 1){
        si += __shfl_xor(si, o, 64);
        sj += __shfl_xor(sj, o, 64);
      }
      if (cg_ == 0){ s_i[row] = si; s_j[row] = sj; }
      ((float4*)(g + row*Dd))[cg_] = a4;
    }
  } else {
    // ---------- topk: 4 waves, one row each; tiled LDS-transposed candidates ----------
    int bb = b;
    if (b == 0){                                // zero stats (replaces memset dispatch)
      #pragma unroll 1
      for (int i = tid; i < NCPY*256; i += 256) stats[i] = 0.f;
    }
    float* eT = (float*)smem;                   // [64][ET_STRIDE] normalized, transposed
    float* se = (float*)(smem + 64*ET_STRIDE*4);// [256] raw query rows (norm is argmax-invariant)
    int wv = tid >> 6, lane = tid & 63;
    se[tid] = embed[bb*256 + tid];              // this block's 4 query rows, coalesced
    const float4* emb4 = (const float4*)embed;
    float av[8];                                // av[rep] = score of candidate rep*64+lane
    #pragma unroll
    for (int tt = 0; tt < 4; tt++){             // 4 tiles x 128 candidate rows
      float4 stg[8];
      #pragma unroll
      for (int j = 0; j < 8; j++)               // fully coalesced: 4KB contiguous per instr
        stg[j] = emb4[tt*2048 + j*256 + tid];   // = row (tt*128 + j*16 + tid>>4), d0=(tid&15)*4
      __syncthreads();                          // prev tile fully consumed before overwrite
      #pragma unroll
      for (int j = 0; j < 8; j++){
        float4 v = stg[j];
        float ss = v.x*v.x + v.y*v.y + v.z*v.z + v.w*v.w;
        #pragma unroll
        for (int o = 1; o < 16; o <<= 1) ss += __shfl_xor(ss, o, 64);  // row sumsq over 16 lanes
        float rn = 1.f/(sqrtf(ss) + 1e-12f);
        int row_local = j*16 + (tid >> 4);
        int d0 = (tid & 15)*4;
        eT[(d0+0)*ET_STRIDE + row_local] = v.x*rn;
        eT[(d0+1)*ET_STRIDE + row_local] = v.y*rn;
        eT[(d0+2)*ET_STRIDE + row_local] = v.z*rn;
        eT[(d0+3)*ET_STRIDE + row_local] = v.w*rn;
      }
      __syncthreads();
      const float4* sef4 = (const float4*)(se + wv*64);
      float a0 = 0.f, a1 = 0.f;
      #pragma unroll
      for (int d4 = 0; d4 < 16; d4++){
        float4 q4 = sef4[d4];                   // uniform addr -> broadcast, conflict-free
        int d = d4*4;
        a0 += q4.x*eT[(d+0)*ET_STRIDE + lane] + q4.y*eT[(d+1)*ET_STRIDE + lane]
            + q4.z*eT[(d+2)*ET_STRIDE + lane] + q4.w*eT[(d+3)*ET_STRIDE + lane];
        a1 += q4.x*eT[(d+0)*ET_STRIDE + 64 + lane] + q4.y*eT[(d+1)*ET_STRIDE + 64 + lane]
            + q4.z*eT[(d+2)*ET_STRIDE + 64 + lane] + q4.w*eT[(d+3)*ET_STRIDE + 64 + lane];
      }
      av[2*tt]   = a0;
      av[2*tt+1] = a1;
    }
    int row = bb*4 + wv;
    #pragma unroll 1
    for (int t = 0; t < Kk; t++){
      float bv = av[0]; int br = 0;
      #pragma unroll
      for (int rep = 1; rep < 8; rep++)
        if (av[rep] > bv){ bv = av[rep]; br = rep; }   // strict > = lowest c per lane
      int ci = br*64 + lane;
      int win = wave_argmax_idx(bv, ci);        // DPP reduce, lowest-index tie-break
      if (lane == 0) topk[row*Kk + t] = win;
      int wr = win >> 6;
      if ((win & 63) == lane){
        #pragma unroll
        for (int rep = 0; rep < 8; rep++)
          if (rep == wr) av[rep] = -INFINITY;
      }
    }
  }
}

// ================= K2: softmax + gather-aggregate + BN1 stats =================
// 2048 blocks: 8 blocks/CU -> 32 waves/CU (100% cap). Each block = 32 nodes.
// Softmax: 2 nodes/wave (one per 32-lane half), 5-step butterfly (offsets 16..1 stay in-half).
__global__ __launch_bounds__(256) void k2(const float* __restrict__ g,
    const float* __restrict__ s_i, const float* __restrict__ s_j,
    const int* __restrict__ topk, const float* __restrict__ bias,
    float* __restrict__ agg, float* __restrict__ stats){
  __shared__ float  swt[4][4][24];
  __shared__ int    sji[4][4][24];
  __shared__ float4 sred_s[4][16], sred_q[4][16];
  __shared__ float4 sbias[16];
  int tid = threadIdx.x, wv = tid >> 6, lane = tid & 63;
  if (tid < 16) sbias[tid] = ((const float4*)bias)[tid];
  __syncthreads();
  // bid%8 preserved -> each batch's g-slab stays on one XCD's L2
  int bid = blockIdx.x;
  int xcd = bid & 7, q = bid >> 3;             // q 0..255
  int batch = xcd*16 + (q & 15);
  int six = q >> 4;                            // 0..15 (sixteenth of a batch)
  int base = batch*Nn;
  int node0 = six*32 + wv*8;                   // 8 nodes per wave
  const float4* g4 = (const float4*)g;
  int h = lane >> 4, c = lane & 15;
  int half = lane >> 5, ln = lane & 31;        // pair-softmax: node index within half
  float4 s4 = {0,0,0,0}, q4 = {0,0,0,0};
  #pragma unroll 1
  for (int gI = 0; gI < 2; gI++){
    #pragma unroll
    for (int pr = 0; pr < 2; pr++){            // 2 pairs = 4 nodes per gI round
      int node = node0 + gI*4 + pr*2 + half;
      int dest = base + node;
      float si_d = s_i[dest];
      float lg = -INFINITY; int j = node;
      if (ln < Kk){
        j = topk[node*Kk + ln];
        if (j != node) lg = leaky(si_d + s_j[base + j]);  // self in topk masked
      } else if (ln == Kk){
        lg = leaky(si_d + s_j[dest]);                     // appended self loop
      }
      float m = lg;
      #pragma unroll
      for (int o = 16; o; o >>= 1) m = fmaxf(m, __shfl_xor(m, o, 64));  // per-half reduce
      float e_ = (ln <= Kk) ? __expf(lg - m) : 0.f;
      float denom = e_;
      #pragma unroll
      for (int o = 16; o; o >>= 1) denom += __shfl_xor(denom, o, 64);
      if (ln < 24){
        swt[wv][pr*2+half][ln] = (ln <= Kk) ? e_/denom : 0.f;
        sji[wv][pr*2+half][ln] = j;
      }
    }
    float la[24]; int ja[24];                 // wave-synchronous LDS readback
    const float4* lv = (const float4*)swt[wv][h];
    const int4*   jv = (const int4*)sji[wv][h];
    #pragma unroll
    for (int qq = 0; qq < 6; qq++){
      float4 f = lv[qq]; la[4*qq]=f.x; la[4*qq+1]=f.y; la[4*qq+2]=f.z; la[4*qq+3]=f.w;
      int4  ii = jv[qq]; ja[4*qq]=ii.x; ja[4*qq+1]=ii.y; ja[4*qq+2]=ii.z; ja[4*qq+3]=ii.w;
    }
    float4 acc = sbias[c];
    #pragma unroll
    for (int e = 0; e <= Kk; e++){
      float4 gv = g4[(base + ja[e])*16 + c];  // 4 dests per gather round
      acc.x += la[e]*gv.x; acc.y += la[e]*gv.y; acc.z += la[e]*gv.z; acc.w += la[e]*gv.w;
    }
    int dest = base + node0 + gI*4 + h;
    ((float4*)agg)[dest*16 + c] = acc;
    s4.x += acc.x; s4.y += acc.y; s4.z += acc.z; s4.w += acc.w;
    q4.x += acc.x*acc.x; q4.y += acc.y*acc.y; q4.z += acc.z*acc.z; q4.w += acc.w*acc.w;
  }
  #pragma unroll
  for (int o = 16; o <= 32; o <<= 1){
    s4.x += __shfl_xor(s4.x,o,64); s4.y += __shfl_xor(s4.y,o,64);
    s4.z += __shfl_xor(s4.z,o,64); s4.w += __shfl_xor(s4.w,o,64);
    q4.x += __shfl_xor(q4.x,o,64); q4.y += __shfl_xor(q4.y,o,64);
    q4.z += __shfl_xor(q4.z,o,64); q4.w += __shfl_xor(q4.w,o,64);
  }
  if (lane < 16){ sred_s[wv][lane] = s4; sred_q[wv][lane] = q4; }
  __syncthreads();
  float* sc = stats + (bid & (NCPY-1))*256;   // replicated accumulators
  if (wv == 0 && lane < 16){
    float4 a = sred_s[0][lane];
    #pragma unroll
    for (int w = 1; w < 4; w++){ float4 t = sred_s[w][lane]; a.x+=t.x; a.y+=t.y; a.z+=t.z; a.w+=t.w; }
    atomicAdd(&sc[lane*4+0], a.x); atomicAdd(&sc[lane*4+1], a.y);
    atomicAdd(&sc[lane*4+2], a.z); atomicAdd(&sc[lane*4+3], a.w);
  }
  if (wv == 1 && lane < 16){
    float4 a = sred_q[0][lane];
    #pragma unroll
    for (int w = 1; w < 4; w++){ float4 t = sred_q[w][lane]; a.x+=t.x; a.y+=t.y; a.z+=t.z; a.w+=t.w; }
    atomicAdd(&sc[64+lane*4+0], a.x); atomicAdd(&sc[64+lane*4+1], a.y);
    atomicAdd(&sc[64+lane*4+2], a.z); atomicAdd(&sc[64+lane*4+3], a.w);
  }
}

// ================= K3: (inline BN1 finalize) + recompute h2 + BN2 stats =================
// 2048 blocks: 8 blocks/CU; 2 strided iters/thread (stride 32768 keeps node const mod 512)
__global__ __launch_bounds__(256) void k3(const float* __restrict__ agg,
    const float* __restrict__ embed, const float* __restrict__ bn1g,
    const float* __restrict__ bn1b, float* __restrict__ stats){
  __shared__ float ssc[64], ssh[64];
  __shared__ float4 sred_s[4][16], sred_q[4][16];
  int tid = threadIdx.x;
  if (tid < 64){
    float s = 0.f, qq = 0.f;
    #pragma unroll
    for (int x = 0; x < NCPY; x++){ s += stats[x*256 + tid]; qq += stats[x*256 + 64 + tid]; }
    float mu = s*(1.f/BN), var = qq*(1.f/BN) - mu*mu;
    float sc = bn1g[tid]/sqrtf(var + 1e-5f);
    ssc[tid] = sc; ssh[tid] = bn1b[tid] - mu*sc;
  }
  __syncthreads();
  int gt = blockIdx.x*256 + tid;
  int c = gt & 15, r0 = gt >> 4;
  int wv = tid >> 6, lane = tid & 63;
  float4 sc1 = ((const float4*)ssc)[c], sh1 = ((const float4*)ssh)[c];
  float4 e4 = ((const float4*)embed)[(r0 & (Nn-1))*16 + c];
  float4 s4 = {0,0,0,0}, q4 = {0,0,0,0};
  const float4* a4 = (const float4*)agg;
  for (int r = r0; r < BN; r += 32768){
    float4 v = a4[r*16 + c];
    v.x = fmaxf(v.x*sc1.x+sh1.x, 0.f)*e4.x;
    v.y = fmaxf(v.y*sc1.y+sh1.y, 0.f)*e4.y;
    v.z = fmaxf(v.z*sc1.z+sh1.z, 0.f)*e4.z;
    v.w = fmaxf(v.w*sc1.w+sh1.w, 0.f)*e4.w;
    s4.x += v.x; s4.y += v.y; s4.z += v.z; s4.w += v.w;
    q4.x += v.x*v.x; q4.y += v.y*v.y; q4.z += v.z*v.z; q4.w += v.w*v.w;
  }
  #pragma unroll
  for (int o = 16; o <= 32; o <<= 1){
    s4.x += __shfl_xor(s4.x,o,64); s4.y += __shfl_xor(s4.y,o,64);
    s4.z += __shfl_xor(s4.z,o,64); s4.w += __shfl_xor(s4.w,o,64);
    q4.x += __shfl_xor(q4.x,o,64); q4.y += __shfl_xor(q4.y,o,64);
    q4.z += __shfl_xor(q4.z,o,64); q4.w += __shfl_xor(q4.w,o,64);
  }
  if (lane < 16){ sred_s[wv][lane] = s4; sred_q[wv][lane] = q4; }
  __syncthreads();
  float* sc = stats + (blockIdx.x & (NCPY-1))*256;
  if (wv == 0 && lane < 16){
    float4 a = sred_s[0][lane];
    #pragma unroll
    for (int w = 1; w < 4; w++){ float4 t = sred_s[w][lane]; a.x+=t.x; a.y+=t.y; a.z+=t.z; a.w+=t.w; }
    atomicAdd(&sc[128+lane*4+0], a.x); atomicAdd(&sc[128+lane*4+1], a.y);
    atomicAdd(&sc[128+lane*4+2], a.z); atomicAdd(&sc[128+lane*4+3], a.w);
  }
  if (wv == 1 && lane < 16){
    float4 a = sred_q[0][lane];
    #pragma unroll
    for (int w = 1; w < 4; w++){ float4 t = sred_q[w][lane]; a.x+=t.x; a.y+=t.y; a.z+=t.z; a.w+=t.w; }
    atomicAdd(&sc[192+lane*4+0], a.x); atomicAdd(&sc[192+lane*4+1], a.y);
    atomicAdd(&sc[192+lane*4+2], a.z); atomicAdd(&sc[192+lane*4+3], a.w);
  }
}

// ================= K4: (inline BN finalize x2) + recompute + output head =================
__global__ __launch_bounds__(256) void k4(const float* __restrict__ agg,
    const float* __restrict__ embed, const float* __restrict__ bn1g,
    const float* __restrict__ bn1b, const float* __restrict__ bn2g,
    const float* __restrict__ bn2b, const float* __restrict__ outW,
    const float* __restrict__ outb, const float* __restrict__ stats,
    float* __restrict__ out){
  __shared__ float ssc1[64], ssh1[64], ssc2[64], ssh2[64];
  int tid = threadIdx.x;
  if (tid < 64){
    float s1=0.f, q1=0.f, s2=0.f, q2=0.f;
    #pragma unroll
    for (int x = 0; x < NCPY; x++){
      const float* p = stats + x*256;
      s1 += p[tid]; q1 += p[64+tid]; s2 += p[128+tid]; q2 += p[192+tid];
    }
    float mu1 = s1*(1.f/BN), var1 = q1*(1.f/BN) - mu1*mu1;
    float sc1 = bn1g[tid]/sqrtf(var1 + 1e-5f);
    ssc1[tid] = sc1; ssh1[tid] = bn1b[tid] - mu1*sc1;
    float mu2 = s2*(1.f/BN), var2 = q2*(1.f/BN) - mu2*mu2;
    float sc2 = bn2g[tid]/sqrtf(var2 + 1e-5f);
    ssc2[tid] = sc2; ssh2[tid] = bn2b[tid] - mu2*sc2;
  }
  __syncthreads();
  int gt = blockIdx.x*256 + tid;
  int c = gt & 15, r0 = gt >> 4;
  float4 sc1 = ((const float4*)ssc1)[c], sh1 = ((const float4*)ssh1)[c];
  float4 sc2 = ((const float4*)ssc2)[c], sh2 = ((const float4*)ssh2)[c];
  float4 ow  = ((const float4*)outW)[c];
  float ob = outb[0];
  float4 e4 = ((const float4*)embed)[(r0 & (Nn-1))*16 + c];
  const float4* a4 = (const float4*)agg;
  for (int r = r0; r < BN; r += 32768){
    float4 v = a4[r*16 + c];
    v.x = fmaxf(v.x*sc1.x+sh1.x, 0.f)*e4.x;
    v.y = fmaxf(v.y*sc1.y+sh1.y, 0.f)*e4.y;
    v.z = fmaxf(v.z*sc1.z+sh1.z, 0.f)*e4.z;
    v.w = fmaxf(v.w*sc1.w+sh1.w, 0.f)*e4.w;
    float t = fmaxf(v.x*sc2.x+sh2.x, 0.f)*ow.x
            + fmaxf(v.y*sc2.y+sh2.y, 0.f)*ow.y
            + fmaxf(v.z*sc2.z+sh2.z, 0.f)*ow.z
            + fmaxf(v.w*sc2.w+sh2.w, 0.f)*ow.w;
    #pragma unroll
    for (int o = 1; o < 16; o <<= 1) t += __shfl_xor(t, o, 64);
    if (c == 0) out[r] = t + ob;
  }
}

extern "C" void kernel_launch(void* const* d_in, const int* in_sizes, int n_in,
                              void* d_out, int out_size, void* d_ws, size_t ws_size,
                              hipStream_t stream){
  const float* data  = (const float*)d_in[0];
  // d_in[1] = org_edge_index — unused by the reference computation
  const float* embed = (const float*)d_in[2];
  const float* W_lin = (const float*)d_in[3];
  const float* att_i = (const float*)d_in[4];
  const float* att_j = (const float*)d_in[5];
  const float* aem_i = (const float*)d_in[6];
  const float* aem_j = (const float*)d_in[7];
  const float* bias  = (const float*)d_in[8];
  const float* g1    = (const float*)d_in[9];
  const float* b1    = (const float*)d_in[10];
  const float* g2    = (const float*)d_in[11];
  const float* b2    = (const float*)d_in[12];
  const float* outW  = (const float*)d_in[13];
  const float* outb  = (const float*)d_in[14];
  float* out = (float*)d_out;

  float* ws    = (float*)d_ws;
  float* g     = ws;                       // 4,194,304 f32 (16 MB)
  float* agg   = ws + 4194304;             // 4,194,304 f32 (16 MB)
  float* s_i   = ws + 8388608;             // 65,536
  float* s_j   = s_i + 65536;              // 65,536
  int*   tk    = (int*)(s_j + 65536);      // 10,240
  float* stats = (float*)(tk + Nn*Kk);     // NCPY x 256 f32 (zeroed by k1 block 0)

  k1<<<1152, 256, 0, stream>>>(data, W_lin, embed, att_i, att_j, aem_i, aem_j,
                               g, s_i, s_j, tk, stats);
  k2<<<2048, 256, 0, stream>>>(g, s_i, s_j, tk, bias, agg, stats);
  k3<<<2048, 256, 0, stream>>>(agg, embed, g1, b1, stats);
  k4<<<2048, 256, 0, stream>>>(agg, embed, g1, b1, g2, b2, outW, outb, stats, out);
}